// Round 4
// baseline (2204.875 us; speedup 1.0000x reference)
//
#include <hip/hip_runtime.h>
#include <hip/hip_bf16.h>
#include <math.h>

// Problem constants
#define B_  1024
#define T_  50
#define IN_ 784
#define N_  128
#define D_  40
#define H_  200
#define R_  4
#define C_  5
#define GAMMA_ 0.95f
#define G4H_ 800             // 4*H
#define PDIM_ 164            // R*(D+1)
#define RD_ 160              // R*D
#define OUTF_ 360            // H + R*D
#define MSZ_ 5120            // N*D
#define MST_ 42              // padded LDS stride for M rows
#define KP_ 800              // padded image K (25*32)

// recurrent GEMM hi/lo packing: K' = 36 k-blocks of 32
#define AKB_ 24
#define BKB_ 36
#define WXP_N 643072
#define W2P_N (BKB_ * G4H_ * 32)   // 921600
#define APK_N (AKB_ * B_ * 32)     // 786432

#define NBLK_ 1024
#define BAR_N (34 * 32)

typedef __bf16 bf16x8 __attribute__((ext_vector_type(8)));
typedef __bf16 bf16x4 __attribute__((ext_vector_type(4)));
typedef float  fx4    __attribute__((ext_vector_type(4)));

__device__ __forceinline__ float sigmoidf_(float x) { return 1.f / (1.f + expf(-x)); }

__device__ __forceinline__ void load_lds16(const void* g, void* l) {
    __builtin_amdgcn_global_load_lds(
        (const __attribute__((address_space(1))) unsigned int*)g,
        (__attribute__((address_space(3))) unsigned int*)l, 16, 0, 0);
}

// ---------------------------------------------------------------------------
// Hierarchical grid barrier: 32 leaf counters (32 blocks each) + master + gen.
// Each counter on its own 128B line. __threadfence() (agent-scope) provides
// release/acquire edges; tid0 runs the acq_rel atomic protocol.
// ---------------------------------------------------------------------------
__device__ __forceinline__ void grid_barrier(unsigned* bar, int tid) {
    __threadfence();
    __syncthreads();
    if (tid == 0) {
        unsigned* leaf   = &bar[(blockIdx.x & 31) * 32];
        unsigned* master = &bar[32 * 32];
        unsigned* gen    = &bar[33 * 32];
        unsigned g0 = __hip_atomic_load(gen, __ATOMIC_RELAXED, __HIP_MEMORY_SCOPE_AGENT);
        unsigned a = __hip_atomic_fetch_add(leaf, 1u, __ATOMIC_ACQ_REL, __HIP_MEMORY_SCOPE_AGENT);
        if (a == 31u) {
            unsigned b2 = __hip_atomic_fetch_add(master, 1u, __ATOMIC_ACQ_REL, __HIP_MEMORY_SCOPE_AGENT);
            if (b2 == 31u) {
                #pragma unroll
                for (int i = 0; i < 32; i++)
                    __hip_atomic_store(&bar[i * 32], 0u, __ATOMIC_RELAXED, __HIP_MEMORY_SCOPE_AGENT);
                __hip_atomic_store(master, 0u, __ATOMIC_RELAXED, __HIP_MEMORY_SCOPE_AGENT);
                __hip_atomic_fetch_add(gen, 1u, __ATOMIC_RELEASE, __HIP_MEMORY_SCOPE_AGENT);
            }
        }
        while (__hip_atomic_load(gen, __ATOMIC_RELAXED, __HIP_MEMORY_SCOPE_AGENT) == g0)
            __builtin_amdgcn_s_sleep(8);
    }
    __syncthreads();
    __threadfence();
}

// ---------------------------------------------------------------------------
// One-time packing (WxP, W2P, WpT) — unchanged.
// ---------------------------------------------------------------------------
__global__ __launch_bounds__(256) void pack_kernel(
    const float* __restrict__ Wx, const float* __restrict__ Wh,
    const float* __restrict__ Wp,
    __bf16* __restrict__ WxP, __bf16* __restrict__ W2P, float* __restrict__ WpT)
{
    int idx = blockIdx.x * 256 + threadIdx.x;
    if (idx < WXP_N) {
        int kb = idx / 25600, rem = idx - kb * 25600;
        int n = rem >> 5, q8 = rem & 31;
        int k = kb * 32 + q8;
        WxP[idx] = (k < IN_ && kb < 25) ? (__bf16)Wx[(size_t)k * G4H_ + n] : (__bf16)0.0f;
    }
    if (idx < W2P_N) {
        int kb = idx / (G4H_ * 32), rem = idx - kb * (G4H_ * 32);
        int n = rem >> 5, q8 = rem & 31;
        int kl = (kb < 12 ? kb : (kb < 24 ? kb - 12 : kb - 24)) * 32 + q8;
        __bf16 o = (__bf16)0.0f;
        if (kl < OUTF_) {
            float v = (kl < H_) ? Wh[(size_t)kl * G4H_ + n]
                                : Wx[(size_t)(789 + kl - H_) * G4H_ + n];
            __bf16 hi = (__bf16)v;
            o = (kb < 24) ? hi : (__bf16)(v - (float)hi);
        }
        W2P[idx] = o;
    }
    if (idx < PDIM_ * H_) {
        int r = idx / H_, k = idx - r * H_;
        WpT[idx] = Wp[(size_t)k * PDIM_ + r];
    }
}

// ---------------------------------------------------------------------------
// init state + zero barrier. (Mg/Cst/wug/wrg kept for the fallback path.)
// ---------------------------------------------------------------------------
__global__ void init_kernel(float* Cst, float* Mg, float* wug, float* wrg,
                            __bf16* Apack, float* scal, unsigned* bar)
{
    size_t i = (size_t)blockIdx.x * blockDim.x + threadIdx.x;
    size_t stride = (size_t)gridDim.x * blockDim.x;
    for (size_t j = i; j < (size_t)B_ * MSZ_; j += stride) Mg[j] = 1e-6f;
    for (size_t j = i; j < (size_t)B_ * H_; j += stride) Cst[j] = 0.f;
    for (size_t j = i; j < (size_t)B_ * N_; j += stride) wug[j] = ((j & (N_ - 1)) == 0) ? 1.f : 0.f;
    for (size_t j = i; j < (size_t)B_ * R_ * N_; j += stride) wrg[j] = ((j & (N_ - 1)) == 0) ? 1.f : 0.f;
    for (size_t j = i; j < (size_t)APK_N; j += stride) {
        int kb = (int)(j >> 15);
        int q8 = (int)(j & 31);
        int kl = (kb % 12) * 32 + q8;
        float v = (kl >= H_ && kl < OUTF_) ? 1e-6f : 0.f;
        __bf16 hi = (__bf16)v;
        Apack[j] = (kb < 12) ? hi : (__bf16)(v - (float)hi);
    }
    for (size_t j = i; j < (size_t)BAR_N; j += stride) bar[j] = 0u;
    if (i < 2) scal[i] = 0.f;
}

// ---------------------------------------------------------------------------
// Convert ALL images to bf16 — unchanged.
// ---------------------------------------------------------------------------
__global__ __launch_bounds__(256) void img_convert(
    const float* __restrict__ images, __bf16* __restrict__ img)
{
    long long gi = (long long)blockIdx.x * 256 + threadIdx.x;
    if (gi * 4 >= (long long)T_ * B_ * KP_) return;
    long long m = (gi * 4) / KP_;
    int k = (int)((gi * 4) - m * KP_);
    int t = (int)(m >> 10), b = (int)(m & (B_ - 1));
    bf16x4 o;
    if (k < IN_) {
        const float4 v = *(const float4*)&images[((size_t)b * T_ + t) * IN_ + k];
        o[0] = (__bf16)v.x; o[1] = (__bf16)v.y; o[2] = (__bf16)v.z; o[3] = (__bf16)v.w;
    } else {
        o[0] = o[1] = o[2] = o[3] = (__bf16)0.0f;
    }
    *(bf16x4*)&img[(size_t)m * KP_ + k] = o;
}

// ---------------------------------------------------------------------------
// Gx precompute — unchanged.
// ---------------------------------------------------------------------------
__global__ __launch_bounds__(256) void gx_mfma(
    const __bf16* __restrict__ img, const __bf16* __restrict__ WxP,
    const int* __restrict__ labels, const float* __restrict__ Wx,
    const float* __restrict__ b_lstm, float* __restrict__ Gx)
{
    __shared__ __bf16 A_lds[4096];
    __shared__ __bf16 B_lds[5120];

    const int tid  = threadIdx.x;
    const int lane = tid & 63, w = tid >> 6;
    const int quad = lane >> 4, ln = lane & 15;
    const int swzl = (ln & 3) ^ ((ln >> 2) & 3);
    const int row0 = blockIdx.x * 128;
    const int n0   = blockIdx.y * 160;
    const int mw   = (w >> 1) * 64;
    const int nw   = (w & 1) * 80;

    fx4 acc[4][5];
    #pragma unroll
    for (int i = 0; i < 4; i++)
        #pragma unroll
        for (int j = 0; j < 5; j++) acc[i][j] = (fx4)0.0f;

    for (int kb = 0; kb < 25; kb++) {
        #pragma unroll
        for (int p = 0; p < 2; p++) {
            int cc = p * 256 + tid;
            int m = cc >> 2, c = cc & 3;
            int q = c ^ ((m & 3) ^ ((m >> 2) & 3));
            load_lds16(img + (size_t)(row0 + m) * KP_ + kb * 32 + q * 8,
                       &A_lds[(size_t)(p * 256 + w * 64) * 8]);
        }
        #pragma unroll
        for (int p = 0; p < 3; p++) {
            if (p * 4 + w < 10) {
                int cc = p * 256 + tid;
                int n = cc >> 2, c = cc & 3;
                int q = c ^ ((n & 3) ^ ((n >> 2) & 3));
                load_lds16(WxP + ((size_t)kb * G4H_ + n0 + n) * 32 + q * 8,
                           &B_lds[(size_t)(p * 256 + w * 64) * 8]);
            }
        }
        __syncthreads();

        bf16x8 a[4], bb[5];
        #pragma unroll
        for (int mi = 0; mi < 4; mi++)
            a[mi] = *(const bf16x8*)&A_lds[((mw + mi * 16 + ln) * 4 + (quad ^ swzl)) * 8];
        #pragma unroll
        for (int ni = 0; ni < 5; ni++)
            bb[ni] = *(const bf16x8*)&B_lds[((nw + ni * 16 + ln) * 4 + (quad ^ swzl)) * 8];
        #pragma unroll
        for (int mi = 0; mi < 4; mi++)
            #pragma unroll
            for (int ni = 0; ni < 5; ni++)
                acc[mi][ni] = __builtin_amdgcn_mfma_f32_16x16x32_bf16(a[mi], bb[ni], acc[mi][ni], 0, 0, 0);
        __syncthreads();
    }

    #pragma unroll
    for (int mi = 0; mi < 4; mi++) {
        #pragma unroll
        for (int rr = 0; rr < 4; rr++) {
            int row = row0 + mw + mi * 16 + quad * 4 + rr;
            int t = row >> 10, b = row & (B_ - 1);
            int lbl = (t > 0) ? labels[b * T_ + t - 1] : -1;
            #pragma unroll
            for (int ni = 0; ni < 5; ni++) {
                int col = n0 + nw + ni * 16 + ln;
                float add = b_lstm[col];
                if (lbl >= 0) add += Wx[(size_t)(IN_ + lbl) * G4H_ + col];
                Gx[(size_t)row * G4H_ + col] = acc[mi][ni][rr] + add;
            }
        }
    }
}

// ---------------------------------------------------------------------------
// FALLBACK PATH: round-1 rec_mfma + step_kernel (verified), used only if
// the persistent kernel cannot reach 4 blocks/CU occupancy.
// ---------------------------------------------------------------------------
__global__ __launch_bounds__(256) void rec_mfma(
    const __bf16* __restrict__ Apack, const __bf16* __restrict__ W2P,
    const float* __restrict__ Gxt, float* __restrict__ gates)
{
    __shared__ __bf16 A_lds[8192];
    __shared__ __bf16 B_lds[4096];

    const int tid  = threadIdx.x;
    const int lane = tid & 63, w = tid >> 6;
    const int quad = lane >> 4, ln = lane & 15;
    const int swzl = (ln & 3) ^ ((ln >> 2) & 3);
    const int row0 = blockIdx.x * 64;
    const int col0 = blockIdx.y * 32;
    const int mw   = (w >> 1) * 32;
    const int nw   = (w & 1) * 16;

    fx4 acc[2];
    acc[0] = (fx4)0.0f; acc[1] = (fx4)0.0f;

    for (int it = 0; it < 9; it++) {
        #pragma unroll
        for (int p = 0; p < 4; p++) {
            int cc = p * 256 + tid;
            int kbl = cc >> 8, row = (cc >> 2) & 63, c = cc & 3;
            int q = c ^ ((row & 3) ^ ((row >> 2) & 3));
            int kbg = it * 4 + kbl;
            int kba = (kbg < AKB_) ? kbg : kbg - AKB_;
            load_lds16(Apack + ((size_t)kba * B_ + row0 + row) * 32 + q * 8,
                       &A_lds[(size_t)(p * 256 + w * 64) * 8]);
        }
        #pragma unroll
        for (int p = 0; p < 2; p++) {
            int cc = p * 256 + tid;
            int kbl = cc >> 7, n = (cc >> 2) & 31, c = cc & 3;
            int q = c ^ ((n & 3) ^ ((n >> 2) & 3));
            int kbg = it * 4 + kbl;
            load_lds16(W2P + ((size_t)kbg * G4H_ + col0 + n) * 32 + q * 8,
                       &B_lds[(size_t)(p * 256 + w * 64) * 8]);
        }
        __syncthreads();

        #pragma unroll
        for (int s = 0; s < 4; s++) {
            bf16x8 a0 = *(const bf16x8*)&A_lds[((s * 64 + mw + ln) * 4 + (quad ^ swzl)) * 8];
            bf16x8 a1 = *(const bf16x8*)&A_lds[((s * 64 + mw + 16 + ln) * 4 + (quad ^ swzl)) * 8];
            bf16x8 b0 = *(const bf16x8*)&B_lds[((s * 32 + nw + ln) * 4 + (quad ^ swzl)) * 8];
            acc[0] = __builtin_amdgcn_mfma_f32_16x16x32_bf16(a0, b0, acc[0], 0, 0, 0);
            acc[1] = __builtin_amdgcn_mfma_f32_16x16x32_bf16(a1, b0, acc[1], 0, 0, 0);
        }
        __syncthreads();
    }

    #pragma unroll
    for (int mi = 0; mi < 2; mi++) {
        #pragma unroll
        for (int rr = 0; rr < 4; rr++) {
            int row = row0 + mw + mi * 16 + quad * 4 + rr;
            int col = col0 + nw + ln;
            gates[(size_t)row * G4H_ + col] = acc[mi][rr] + Gxt[(size_t)row * G4H_ + col];
        }
    }
}

__global__ __launch_bounds__(256) void step_kernel(
    const float* __restrict__ gates, __bf16* __restrict__ Apack, float* __restrict__ Cst,
    float* __restrict__ Mg, float* __restrict__ wug, float* __restrict__ wrg,
    const float* __restrict__ WpT, const float* __restrict__ bp,
    const float* __restrict__ Wc, const float* __restrict__ bc,
    float* __restrict__ out, int t)
{
    const int b = blockIdx.x;
    const int tid = threadIdx.x;
    const int lane = tid & 63, w = tid >> 6;
    const int nn = tid >> 1, dh = tid & 1, d0 = dh * 20;

    __shared__ float M_s[N_ * MST_];
    __shared__ float h_s[H_];
    __shared__ float k_s[RD_];
    __shared__ float sig_s[R_];
    __shared__ float wu_s[N_];
    __shared__ int   lu_s[R_];
    __shared__ float wrn_s[R_ * N_];
    __shared__ float ww_s[R_ * N_];
    __shared__ float rn_s[RD_];
    __shared__ float red[160];

    float m[20];

    if (tid < H_) {
        const float gi = gates[(size_t)b * G4H_ + tid];
        const float gf = gates[(size_t)b * G4H_ + H_ + tid];
        const float gg = gates[(size_t)b * G4H_ + 2 * H_ + tid];
        const float go = gates[(size_t)b * G4H_ + 3 * H_ + tid];
        const float c_old = Cst[b * H_ + tid];
        const float cn = sigmoidf_(gf) * c_old + sigmoidf_(gi) * tanhf(gg);
        const float hn = sigmoidf_(go) * tanhf(cn);
        Cst[b * H_ + tid] = cn;
        h_s[tid] = hn;
        __bf16 hi = (__bf16)hn;
        __bf16 lo = (__bf16)(hn - (float)hi);
        const int kb = tid >> 5, q8 = tid & 31;
        Apack[((size_t)kb * B_ + b) * 32 + q8] = hi;
        Apack[((size_t)(kb + 12) * B_ + b) * 32 + q8] = lo;
    }
    if (tid < N_) wu_s[tid] = wug[b * N_ + tid];
    {
        const float* src = Mg + (size_t)b * MSZ_ + nn * D_ + d0;
        #pragma unroll
        for (int j = 0; j < 20; j += 4) {
            float4 v = *(const float4*)&src[j];
            m[j] = v.x; m[j + 1] = v.y; m[j + 2] = v.z; m[j + 3] = v.w;
        }
    }
    __syncthreads();

    if (tid < PDIM_) {
        float acc = bp[tid];
        const float* wr = WpT + (size_t)tid * H_;
        #pragma unroll 5
        for (int k2 = 0; k2 < H_; k2 += 4) {
            float4 wv = *(const float4*)&wr[k2];
            float4 hv = *(const float4*)&h_s[k2];
            acc += hv.x * wv.x + hv.y * wv.y + hv.z * wv.z + hv.w * wv.w;
        }
        int r = tid / (D_ + 1), d = tid - r * (D_ + 1);
        if (d < D_) k_s[r * D_ + d] = tanhf(acc);
        else        sig_s[r] = sigmoidf_(acc);
    }
    if (w == 3) {
        float v0 = wu_s[lane], v1 = wu_s[lane + 64];
        #pragma unroll
        for (int r4 = 0; r4 < R_; r4++) {
            float v; int idx;
            if (v1 < v0) { v = v1; idx = lane + 64; } else { v = v0; idx = lane; }
            #pragma unroll
            for (int off = 32; off > 0; off >>= 1) {
                float ov = __shfl_down(v, off);
                int   oi = __shfl_down(idx, off);
                if (ov < v || (ov == v && oi < idx)) { v = ov; idx = oi; }
            }
            int bi = __shfl(idx, 0);
            if (lane == 0) lu_s[r4] = bi;
            if (lane == bi) v0 = 3.0e38f;
            if (lane + 64 == bi) v1 = 3.0e38f;
        }
    }
    __syncthreads();

    {
        float nr = 0.f;
        #pragma unroll
        for (int j = 0; j < 20; j++) nr += m[j] * m[j];
        float dt[4];
        #pragma unroll
        for (int r = 0; r < 4; r++) {
            float s = 0.f;
            const float* kr = &k_s[r * D_ + d0];
            #pragma unroll
            for (int j = 0; j < 20; j += 4) {
                float4 kv = *(const float4*)&kr[j];
                s += m[j] * kv.x + m[j + 1] * kv.y + m[j + 2] * kv.z + m[j + 3] * kv.w;
            }
            dt[r] = s;
        }
        nr += __shfl_xor(nr, 1);
        #pragma unroll
        for (int r = 0; r < 4; r++) dt[r] += __shfl_xor(dt[r], 1);
        const float den = sqrtf(nr) + 1e-8f;
        if (dh == 0) { wrn_s[nn] = dt[0] / den;          wrn_s[N_ + nn] = dt[1] / den; }
        else         { wrn_s[2 * N_ + nn] = dt[2] / den; wrn_s[3 * N_ + nn] = dt[3] / den; }
    }
    __syncthreads();

    {
        const int r = w;
        float kv = (lane < D_) ? k_s[r * D_ + lane] * k_s[r * D_ + lane] : 0.f;
        #pragma unroll
        for (int off = 32; off > 0; off >>= 1) kv += __shfl_xor(kv, off);
        const float kinv = 1.f / (sqrtf(kv) + 1e-8f);

        const int n0i = lane, n1i = lane + 64;
        float s0 = wrn_s[r * N_ + n0i] * kinv;
        float s1 = wrn_s[r * N_ + n1i] * kinv;
        const float sg = sig_s[r];
        float wlu0 = (n0i == lu_s[0] || n0i == lu_s[1] || n0i == lu_s[2] || n0i == lu_s[3]) ? 1.f : 0.f;
        float wlu1 = (n1i == lu_s[0] || n1i == lu_s[1] || n1i == lu_s[2] || n1i == lu_s[3]) ? 1.f : 0.f;
        ww_s[r * N_ + n0i] = sg * wrg[(size_t)b * (R_ * N_) + r * N_ + n0i] + (1.f - sg) * wlu0;
        ww_s[r * N_ + n1i] = sg * wrg[(size_t)b * (R_ * N_) + r * N_ + n1i] + (1.f - sg) * wlu1;
        float mx = fmaxf(s0, s1);
        #pragma unroll
        for (int off = 32; off > 0; off >>= 1) mx = fmaxf(mx, __shfl_xor(mx, off));
        float e0 = expf(s0 - mx), e1 = expf(s1 - mx);
        float sm = e0 + e1;
        #pragma unroll
        for (int off = 32; off > 0; off >>= 1) sm += __shfl_xor(sm, off);
        const float inv = 1.f / sm;
        e0 *= inv; e1 *= inv;
        wrn_s[r * N_ + n0i] = e0;
        wrn_s[r * N_ + n1i] = e1;
        wrg[(size_t)b * (R_ * N_) + r * N_ + n0i] = e0;
        wrg[(size_t)b * (R_ * N_) + r * N_ + n1i] = e1;
    }
    __syncthreads();

    if (tid < N_) {
        float acc = GAMMA_ * wu_s[tid];
        #pragma unroll
        for (int r = 0; r < R_; r++) acc += wrn_s[r * N_ + tid] + ww_s[r * N_ + tid];
        wug[b * N_ + tid] = acc;
    }
    {
        const int lu4 = lu_s[3];
        if (nn == lu4) {
            #pragma unroll
            for (int j = 0; j < 20; j++) m[j] = 0.f;
        }
        float wgt[4];
        #pragma unroll
        for (int r = 0; r < 4; r++) wgt[r] = ww_s[r * N_ + nn];
        #pragma unroll
        for (int r = 0; r < 4; r++) {
            const float* kr = &k_s[r * D_ + d0];
            const float g = wgt[r];
            #pragma unroll
            for (int j = 0; j < 20; j += 4) {
                float4 kv = *(const float4*)&kr[j];
                m[j]     += g * kv.x;
                m[j + 1] += g * kv.y;
                m[j + 2] += g * kv.z;
                m[j + 3] += g * kv.w;
            }
        }
        float* mrow = &M_s[nn * MST_ + d0];
        float* gdst = Mg + (size_t)b * MSZ_ + nn * D_ + d0;
        #pragma unroll
        for (int j = 0; j < 20; j += 4) {
            *(float2*)&mrow[j]     = make_float2(m[j], m[j + 1]);
            *(float2*)&mrow[j + 2] = make_float2(m[j + 2], m[j + 3]);
            *(float4*)&gdst[j]     = make_float4(m[j], m[j + 1], m[j + 2], m[j + 3]);
        }
    }
    __syncthreads();

    if (tid < RD_) {
        const int r = tid / D_, d = tid - r * D_;
        const float* wrow = &wrn_s[r * N_];
        float a0 = 0.f, a1 = 0.f, a2 = 0.f, a3 = 0.f;
        #pragma unroll 8
        for (int n2 = 0; n2 < N_; n2 += 4) {
            float4 wv = *(const float4*)&wrow[n2];
            a0 += wv.x * M_s[(n2 + 0) * MST_ + d];
            a1 += wv.y * M_s[(n2 + 1) * MST_ + d];
            a2 += wv.z * M_s[(n2 + 2) * MST_ + d];
            a3 += wv.w * M_s[(n2 + 3) * MST_ + d];
        }
        const float acc = (a0 + a1) + (a2 + a3);
        rn_s[tid] = acc;
        __bf16 hi = (__bf16)acc;
        __bf16 lo = (__bf16)(acc - (float)hi);
        const int kp = H_ + tid;
        const int kb = kp >> 5, q8 = kp & 31;
        Apack[((size_t)kb * B_ + b) * 32 + q8] = hi;
        Apack[((size_t)(kb + 12) * B_ + b) * 32 + q8] = lo;
    }
    __syncthreads();

    if (tid < 160) {
        int c = tid >> 5, seg = tid & 31;
        float acc = 0.f;
        for (int j = seg; j < OUTF_; j += 32) {
            float v = (j < H_) ? h_s[j] : rn_s[j - H_];
            acc += v * Wc[j * C_ + c];
        }
        red[tid] = acc;
    }
    __syncthreads();

    if (w == 0) {
        float lg = 0.f;
        if (lane < C_) {
            lg = bc[lane];
            #pragma unroll
            for (int s = 0; s < 32; s++) lg += red[lane * 32 + s];
        }
        float l0 = __shfl(lg, 0), l1 = __shfl(lg, 1), l2 = __shfl(lg, 2);
        float l3 = __shfl(lg, 3), l4 = __shfl(lg, 4);
        if (lane == 0) {
            float mx = fmaxf(fmaxf(fmaxf(l0, l1), fmaxf(l2, l3)), l4);
            float e0 = expf(l0 - mx), e1 = expf(l1 - mx), e2 = expf(l2 - mx);
            float e3 = expf(l3 - mx), e4 = expf(l4 - mx);
            float inv = 1.f / (e0 + e1 + e2 + e3 + e4);
            float* o = out + ((size_t)b * T_ + t) * C_;
            o[0] = e0 * inv; o[1] = e1 * inv; o[2] = e2 * inv; o[3] = e3 * inv; o[4] = e4 * inv;
        }
    }
}

// ---------------------------------------------------------------------------
// PERSISTENT FUSED t-LOOP (plain launch, capacity-guaranteed co-residency).
// 1024 blocks x 256 thr = exactly 4 blocks/CU x 256 CU; launch only after
// the occupancy query confirms >=4 blocks/CU. Per-sample state in regs/LDS
// for all 50 steps. Blocks 0..399 run the rec GEMM tile each t.
// ---------------------------------------------------------------------------
__global__ __launch_bounds__(256, 4) void fused_loop(
    __bf16* __restrict__ Apack, const __bf16* __restrict__ W2P,
    const float* __restrict__ Gx, float* __restrict__ gates,
    const float* __restrict__ WpT, const float* __restrict__ bp,
    const float* __restrict__ Wc, const float* __restrict__ bc,
    float* __restrict__ out, unsigned* bar)
{
    __shared__ float Msh[6144];        // union: GEMM staging (24KB) | M_s[128][42]
    __shared__ float h_s[H_];
    __shared__ float k_s[RD_];
    __shared__ float sig_s[R_];
    __shared__ float wu_s[N_];
    __shared__ int   lu_s[R_];
    __shared__ float wrn_s[R_ * N_];
    __shared__ float ww_s[R_ * N_];
    __shared__ float rn_s[RD_];
    __shared__ float red[160];

    const int tid  = threadIdx.x;
    const int lane = tid & 63, w = tid >> 6;
    const int b    = blockIdx.x;
    const int nn = tid >> 1, dh = tid & 1, d0 = dh * 20;
    const int quad = lane >> 4, ln = lane & 15;
    const int swzl = (ln & 3) ^ ((ln >> 2) & 3);

    // persistent per-sample state
    float m[20];
    #pragma unroll
    for (int j = 0; j < 20; j++) m[j] = 1e-6f;
    float c_reg = 0.f;
    float wr0 = (lane == 0) ? 1.f : 0.f;   // wr[w][lane]
    float wr1 = 0.f;                        // wr[w][lane+64]
    if (tid < N_) wu_s[tid] = (tid == 0) ? 1.f : 0.f;
    __syncthreads();

    // GEMM tile mapping (blocks 0..399): 16 row-tiles x 25 col-tiles
    const int row0 = (b & 15) * 64;
    const int col0 = (b >> 4) * 32;
    const int mw   = (w >> 1) * 32;
    const int nw   = (w & 1) * 16;
    __bf16* A_lds = (__bf16*)Msh;           // 16 KB
    __bf16* B_lds = (__bf16*)Msh + 8192;    // 8 KB
    float*  M_s   = Msh;                    // stride MST_

    for (int t = 0; t < T_; t++) {
        // ===== phase 1: gates = S@W2 + Gx[t]  (blocks 0..399) =====
        if (b < 400) {
            fx4 acc0 = (fx4)0.0f, acc1 = (fx4)0.0f;
            for (int it = 0; it < 9; it++) {
                #pragma unroll
                for (int p = 0; p < 4; p++) {
                    int cc = p * 256 + tid;
                    int kbl = cc >> 8, row = (cc >> 2) & 63, c = cc & 3;
                    int q = c ^ ((row & 3) ^ ((row >> 2) & 3));
                    int kbg = it * 4 + kbl;
                    int kba = (kbg < AKB_) ? kbg : kbg - AKB_;
                    load_lds16(Apack + ((size_t)kba * B_ + row0 + row) * 32 + q * 8,
                               &A_lds[(size_t)(p * 256 + w * 64) * 8]);
                }
                #pragma unroll
                for (int p = 0; p < 2; p++) {
                    int cc = p * 256 + tid;
                    int kbl = cc >> 7, n = (cc >> 2) & 31, c = cc & 3;
                    int q = c ^ ((n & 3) ^ ((n >> 2) & 3));
                    int kbg = it * 4 + kbl;
                    load_lds16(W2P + ((size_t)kbg * G4H_ + col0 + n) * 32 + q * 8,
                               &B_lds[(size_t)(p * 256 + w * 64) * 8]);
                }
                __syncthreads();
                #pragma unroll
                for (int s = 0; s < 4; s++) {
                    bf16x8 a0 = *(const bf16x8*)&A_lds[((s * 64 + mw + ln) * 4 + (quad ^ swzl)) * 8];
                    bf16x8 a1 = *(const bf16x8*)&A_lds[((s * 64 + mw + 16 + ln) * 4 + (quad ^ swzl)) * 8];
                    bf16x8 b0 = *(const bf16x8*)&B_lds[((s * 32 + nw + ln) * 4 + (quad ^ swzl)) * 8];
                    acc0 = __builtin_amdgcn_mfma_f32_16x16x32_bf16(a0, b0, acc0, 0, 0, 0);
                    acc1 = __builtin_amdgcn_mfma_f32_16x16x32_bf16(a1, b0, acc1, 0, 0, 0);
                }
                __syncthreads();
            }
            const float* Gxt = Gx + (size_t)t * B_ * G4H_;
            #pragma unroll
            for (int mi = 0; mi < 2; mi++) {
                fx4 acc = mi ? acc1 : acc0;
                #pragma unroll
                for (int rr = 0; rr < 4; rr++) {
                    int row = row0 + mw + mi * 16 + quad * 4 + rr;
                    int col = col0 + nw + ln;
                    gates[(size_t)row * G4H_ + col] = acc[rr] + Gxt[(size_t)row * G4H_ + col];
                }
            }
        }
        grid_barrier(bar, tid);

        // ===== phase 2: per-sample step (all 1024 blocks, sample = b) =====
        // P1: LSTM
        if (tid < H_) {
            const float gi = gates[(size_t)b * G4H_ + tid];
            const float gf = gates[(size_t)b * G4H_ + H_ + tid];
            const float gg = gates[(size_t)b * G4H_ + 2 * H_ + tid];
            const float go = gates[(size_t)b * G4H_ + 3 * H_ + tid];
            const float cn = sigmoidf_(gf) * c_reg + sigmoidf_(gi) * tanhf(gg);
            const float hn = sigmoidf_(go) * tanhf(cn);
            c_reg = cn;
            h_s[tid] = hn;
            __bf16 hi = (__bf16)hn;
            __bf16 lo = (__bf16)(hn - (float)hi);
            const int kb = tid >> 5, q8 = tid & 31;
            Apack[((size_t)kb * B_ + b) * 32 + q8] = hi;
            Apack[((size_t)(kb + 12) * B_ + b) * 32 + q8] = lo;
        }
        __syncthreads();

        // P2: Wp projection || top-4 least-used (wave 3)
        if (tid < PDIM_) {
            float acc = bp[tid];
            const float* wr = WpT + (size_t)tid * H_;
            #pragma unroll 5
            for (int k2 = 0; k2 < H_; k2 += 4) {
                float4 wv = *(const float4*)&wr[k2];
                float4 hv = *(const float4*)&h_s[k2];
                acc += hv.x * wv.x + hv.y * wv.y + hv.z * wv.z + hv.w * wv.w;
            }
            int r = tid / (D_ + 1), d = tid - r * (D_ + 1);
            if (d < D_) k_s[r * D_ + d] = tanhf(acc);
            else        sig_s[r] = sigmoidf_(acc);
        }
        if (w == 3) {
            float v0 = wu_s[lane], v1 = wu_s[lane + 64];
            #pragma unroll
            for (int r4 = 0; r4 < R_; r4++) {
                float v; int idx;
                if (v1 < v0) { v = v1; idx = lane + 64; } else { v = v0; idx = lane; }
                #pragma unroll
                for (int off = 32; off > 0; off >>= 1) {
                    float ov = __shfl_down(v, off);
                    int   oi = __shfl_down(idx, off);
                    if (ov < v || (ov == v && oi < idx)) { v = ov; idx = oi; }
                }
                int bi = __shfl(idx, 0);
                if (lane == 0) lu_s[r4] = bi;
                if (lane == bi) v0 = 3.0e38f;
                if (lane + 64 == bi) v1 = 3.0e38f;
            }
        }
        __syncthreads();

        // P3: cosine scores from register M
        {
            float nr = 0.f;
            #pragma unroll
            for (int j = 0; j < 20; j++) nr += m[j] * m[j];
            float dt[4];
            #pragma unroll
            for (int r = 0; r < 4; r++) {
                float s = 0.f;
                const float* kr = &k_s[r * D_ + d0];
                #pragma unroll
                for (int j = 0; j < 20; j += 4) {
                    float4 kv = *(const float4*)&kr[j];
                    s += m[j] * kv.x + m[j + 1] * kv.y + m[j + 2] * kv.z + m[j + 3] * kv.w;
                }
                dt[r] = s;
            }
            nr += __shfl_xor(nr, 1);
            #pragma unroll
            for (int r = 0; r < 4; r++) dt[r] += __shfl_xor(dt[r], 1);
            const float den = sqrtf(nr) + 1e-8f;
            if (dh == 0) { wrn_s[nn] = dt[0] / den;          wrn_s[N_ + nn] = dt[1] / den; }
            else         { wrn_s[2 * N_ + nn] = dt[2] / den; wrn_s[3 * N_ + nn] = dt[3] / den; }
        }
        __syncthreads();

        // P4: per-head softmax + write weights (wr in registers)
        {
            const int r = w;
            float kv = (lane < D_) ? k_s[r * D_ + lane] * k_s[r * D_ + lane] : 0.f;
            #pragma unroll
            for (int off = 32; off > 0; off >>= 1) kv += __shfl_xor(kv, off);
            const float kinv = 1.f / (sqrtf(kv) + 1e-8f);

            const int n0i = lane, n1i = lane + 64;
            float s0 = wrn_s[r * N_ + n0i] * kinv;
            float s1 = wrn_s[r * N_ + n1i] * kinv;
            const float sg = sig_s[r];
            float wlu0 = (n0i == lu_s[0] || n0i == lu_s[1] || n0i == lu_s[2] || n0i == lu_s[3]) ? 1.f : 0.f;
            float wlu1 = (n1i == lu_s[0] || n1i == lu_s[1] || n1i == lu_s[2] || n1i == lu_s[3]) ? 1.f : 0.f;
            ww_s[r * N_ + n0i] = sg * wr0 + (1.f - sg) * wlu0;
            ww_s[r * N_ + n1i] = sg * wr1 + (1.f - sg) * wlu1;
            float mx = fmaxf(s0, s1);
            #pragma unroll
            for (int off = 32; off > 0; off >>= 1) mx = fmaxf(mx, __shfl_xor(mx, off));
            float e0 = expf(s0 - mx), e1 = expf(s1 - mx);
            float sm = e0 + e1;
            #pragma unroll
            for (int off = 32; off > 0; off >>= 1) sm += __shfl_xor(sm, off);
            const float inv = 1.f / sm;
            e0 *= inv; e1 *= inv;
            wrn_s[r * N_ + n0i] = e0;
            wrn_s[r * N_ + n1i] = e1;
            wr0 = e0; wr1 = e1;
        }
        __syncthreads();

        // P5: usage update (in-place LDS) + memory erase/write (register M)
        if (tid < N_) {
            float acc = GAMMA_ * wu_s[tid];
            #pragma unroll
            for (int r = 0; r < R_; r++) acc += wrn_s[r * N_ + tid] + ww_s[r * N_ + tid];
            wu_s[tid] = acc;
        }
        {
            const int lu4 = lu_s[3];
            if (nn == lu4) {
                #pragma unroll
                for (int j = 0; j < 20; j++) m[j] = 0.f;
            }
            float wgt[4];
            #pragma unroll
            for (int r = 0; r < 4; r++) wgt[r] = ww_s[r * N_ + nn];
            #pragma unroll
            for (int r = 0; r < 4; r++) {
                const float* kr = &k_s[r * D_ + d0];
                const float g = wgt[r];
                #pragma unroll
                for (int j = 0; j < 20; j += 4) {
                    float4 kv = *(const float4*)&kr[j];
                    m[j]     += g * kv.x;
                    m[j + 1] += g * kv.y;
                    m[j + 2] += g * kv.z;
                    m[j + 3] += g * kv.w;
                }
            }
            float* mrow = &M_s[nn * MST_ + d0];
            #pragma unroll
            for (int j = 0; j < 20; j += 4) {
                *(float2*)&mrow[j]     = make_float2(m[j], m[j + 1]);
                *(float2*)&mrow[j + 2] = make_float2(m[j + 2], m[j + 3]);
            }
        }
        __syncthreads();

        // P6: read vectors; write r to Apack (hi/lo)
        if (tid < RD_) {
            const int r = tid / D_, d = tid - r * D_;
            const float* wrow = &wrn_s[r * N_];
            float a0 = 0.f, a1 = 0.f, a2 = 0.f, a3 = 0.f;
            #pragma unroll 8
            for (int n2 = 0; n2 < N_; n2 += 4) {
                float4 wv = *(const float4*)&wrow[n2];
                a0 += wv.x * M_s[(n2 + 0) * MST_ + d];
                a1 += wv.y * M_s[(n2 + 1) * MST_ + d];
                a2 += wv.z * M_s[(n2 + 2) * MST_ + d];
                a3 += wv.w * M_s[(n2 + 3) * MST_ + d];
            }
            const float acc = (a0 + a1) + (a2 + a3);
            rn_s[tid] = acc;
            __bf16 hi = (__bf16)acc;
            __bf16 lo = (__bf16)(acc - (float)hi);
            const int kp = H_ + tid;
            const int kb = kp >> 5, q8 = kp & 31;
            Apack[((size_t)kb * B_ + b) * 32 + q8] = hi;
            Apack[((size_t)(kb + 12) * B_ + b) * 32 + q8] = lo;
        }
        __syncthreads();

        // P7: logits partials
        if (tid < 160) {
            int c = tid >> 5, seg = tid & 31;
            float acc = 0.f;
            for (int j = seg; j < OUTF_; j += 32) {
                float v = (j < H_) ? h_s[j] : rn_s[j - H_];
                acc += v * Wc[j * C_ + c];
            }
            red[tid] = acc;
        }
        __syncthreads();

        // P8: finish logits, softmax, write probs
        if (w == 0) {
            float lg = 0.f;
            if (lane < C_) {
                lg = bc[lane];
                #pragma unroll
                for (int s = 0; s < 32; s++) lg += red[lane * 32 + s];
            }
            float l0 = __shfl(lg, 0), l1 = __shfl(lg, 1), l2 = __shfl(lg, 2);
            float l3 = __shfl(lg, 3), l4 = __shfl(lg, 4);
            if (lane == 0) {
                float mx = fmaxf(fmaxf(fmaxf(l0, l1), fmaxf(l2, l3)), l4);
                float e0 = expf(l0 - mx), e1 = expf(l1 - mx), e2 = expf(l2 - mx);
                float e3 = expf(l3 - mx), e4 = expf(l4 - mx);
                float inv = 1.f / (e0 + e1 + e2 + e3 + e4);
                float* o = out + ((size_t)b * T_ + t) * C_;
                o[0] = e0 * inv; o[1] = e1 * inv; o[2] = e2 * inv; o[3] = e3 * inv; o[4] = e4 * inv;
            }
        }
        grid_barrier(bar, tid);
    }
}

// ---------------------------------------------------------------------------
// loss — unchanged.
// ---------------------------------------------------------------------------
__global__ __launch_bounds__(256) void loss_kernel(
    const float* __restrict__ out, const int* __restrict__ labels, float* __restrict__ la)
{
    int row = blockIdx.x * 256 + threadIdx.x;
    float li = 0.f, ai = 0.f;
    if (row < B_ * T_) {
        float p[C_];
        #pragma unroll
        for (int c = 0; c < C_; c++) p[c] = out[(size_t)row * C_ + c];
        int tgt = labels[row];
        float mx = p[0];
        #pragma unroll
        for (int c = 1; c < C_; c++) mx = fmaxf(mx, p[c]);
        float sm = 0.f;
        #pragma unroll
        for (int c = 0; c < C_; c++) sm += expf(p[c] - mx);
        li = (mx + logf(sm) - p[tgt]) * (1.f / (B_ * T_));
        int pred = 0; float bv = p[0];
        #pragma unroll
        for (int c = 1; c < C_; c++) if (p[c] > bv) { bv = p[c]; pred = c; }
        ai = (pred == tgt) ? (1.f / (B_ * T_)) : 0.f;
    }
    for (int off = 32; off > 0; off >>= 1) {
        li += __shfl_down(li, off);
        ai += __shfl_down(ai, off);
    }
    if ((threadIdx.x & 63) == 0) {
        atomicAdd(&la[0], li);
        atomicAdd(&la[1], ai);
    }
}

extern "C" void kernel_launch(void* const* d_in, const int* in_sizes, int n_in,
                              void* d_out, int out_size, void* d_ws, size_t ws_size,
                              hipStream_t stream)
{
    const float* images = (const float*)d_in[0];
    const int*   labels = (const int*)d_in[1];
    const float* Wx     = (const float*)d_in[2];
    const float* Wh     = (const float*)d_in[3];
    const float* b_lstm = (const float*)d_in[4];
    const float* Wp     = (const float*)d_in[5];
    const float* bp     = (const float*)d_in[6];
    const float* Wc     = (const float*)d_in[7];
    const float* bc     = (const float*)d_in[8];
    float* out = (float*)d_out;

    float* ws = (float*)d_ws;
    float* gates = ws;                             // 1024*800
    float* Cst   = gates + (size_t)B_ * G4H_;      // 1024*200
    float* Mg    = Cst   + (size_t)B_ * H_;        // 1024*5120
    float* wug   = Mg    + (size_t)B_ * MSZ_;      // 1024*128
    float* wrg   = wug   + (size_t)B_ * N_;        // 1024*512
    float* Gx    = wrg   + (size_t)B_ * R_ * N_;   // 50*1024*800 f32 (164 MB)
    __bf16* imgb = (__bf16*)(Gx + (size_t)T_ * B_ * G4H_);   // 50*1024*800 bf16 (82 MB)
    __bf16* WxP  = imgb + (size_t)T_ * B_ * KP_;             // 643072
    __bf16* W2P  = WxP  + (size_t)WXP_N;                     // 921600
    __bf16* Apack = W2P + (size_t)W2P_N;                     // 786432
    float*  WpT  = (float*)(Apack + (size_t)APK_N);          // 164*200 f32
    unsigned* bar = (unsigned*)(WpT + (size_t)PDIM_ * H_);   // 34*32 uints

    pack_kernel<<<(W2P_N + 255) / 256, 256, 0, stream>>>(Wx, Wh, Wp, WxP, W2P, WpT);
    init_kernel<<<1024, 256, 0, stream>>>(Cst, Mg, wug, wrg, Apack, out + (size_t)B_ * T_ * C_, bar);

    img_convert<<<(int)(((long long)T_ * B_ * KP_ / 4 + 255) / 256), 256, 0, stream>>>(images, imgb);
    gx_mfma<<<dim3(T_ * B_ / 128, 5), 256, 0, stream>>>(imgb, WxP, labels, Wx, b_lstm, Gx);

    // Persistent t-loop via PLAIN launch (graph-capture-safe). Co-residency of
    // all 1024 blocks (4/CU x 256 CU) is verified with a pure occupancy query;
    // if <4 blocks/CU the verified two-kernel path runs instead.
    int blocksPerCU = 0;
    hipError_t qerr = hipOccupancyMaxActiveBlocksPerMultiprocessor(
        &blocksPerCU, fused_loop, 256, 0);
    if (qerr == hipSuccess && blocksPerCU >= 4) {
        fused_loop<<<NBLK_, 256, 0, stream>>>(
            Apack, W2P, Gx, gates, WpT, bp, Wc, bc, out, bar);
    } else {
        for (int t = 0; t < T_; t++) {
            rec_mfma<<<dim3(B_ / 64, G4H_ / 32), 256, 0, stream>>>(
                Apack, W2P, Gx + (size_t)t * B_ * G4H_, gates);
            step_kernel<<<B_, 256, 0, stream>>>(
                gates, Apack, Cst, Mg, wug, wrg, WpT, bp, Wc, bc, out, t);
        }
    }

    loss_kernel<<<(B_ * T_) / 256, 256, 0, stream>>>(out, labels, out + (size_t)B_ * T_ * C_);
}

// Round 6
// 1871.367 us; speedup vs baseline: 1.1782x; 1.1782x over previous
//
#include <hip/hip_runtime.h>
#include <hip/hip_bf16.h>
#include <math.h>

// Problem constants
#define B_  1024
#define T_  50
#define IN_ 784
#define N_  128
#define D_  40
#define H_  200
#define R_  4
#define C_  5
#define GAMMA_ 0.95f
#define G4H_ 800             // 4*H
#define PDIM_ 164            // R*(D+1)
#define RD_ 160              // R*D
#define OUTF_ 360            // H + R*D
#define MSZ_ 5120            // N*D
#define MST_ 42              // padded LDS stride for M rows
#define KP_ 800              // padded image K (25*32)
#define GSTR_ 1024           // gates row stride: 800 gate cols + 164 Wp cols + pad

// recurrent GEMM hi/lo packing: K' = 36 k-blocks of 32 (12 hi + 12 hi(pairs A-lo) + 12 lo)
#define AKB_ 24              // A k-blocks stored (hi 0..11, lo 12..23); block 24+i maps to i
#define BKB_ 36
#define WXP_N 643072
#define W2P_N (BKB_ * GSTR_ * 32)   // 1179648: B-cols extended to 1024 (800 gates | 164 Wp | pad)
#define APK_N (AKB_ * B_ * 32)      // 786432

typedef __bf16 bf16x8 __attribute__((ext_vector_type(8)));
typedef __bf16 bf16x4 __attribute__((ext_vector_type(4)));
typedef float  fx4    __attribute__((ext_vector_type(4)));

__device__ __forceinline__ float sigmoidf_(float x) { return 1.f / (1.f + expf(-x)); }

__device__ __forceinline__ void load_lds16(const void* g, void* l) {
    __builtin_amdgcn_global_load_lds(
        (const __attribute__((address_space(1))) unsigned int*)g,
        (__attribute__((address_space(3))) unsigned int*)l, 16, 0, 0);
}

// ---------------------------------------------------------------------------
// One-time packing.
// WxP: bf16 MFMA-B layout of Wx(0:784), K padded to 800.
// W2P: hi/lo bf16 B layout, 1024 columns:
//   cols 0..799   : W2 = [Wh ; Wx(789:949)]  (K=360, pad 384)   -> gates
//   cols 800..963 : Wp (rows 0..199, zero above)                -> p = h@Wp
//   cols 964..1023: zero pad
//   kb 0..11 -> hi (pairs A hi), 12..23 -> hi (pairs A lo), 24..35 -> lo
// ---------------------------------------------------------------------------
__global__ __launch_bounds__(256) void pack_kernel(
    const float* __restrict__ Wx, const float* __restrict__ Wh,
    const float* __restrict__ Wp,
    __bf16* __restrict__ WxP, __bf16* __restrict__ W2P)
{
    int idx = blockIdx.x * 256 + threadIdx.x;
    if (idx < WXP_N) {
        int kb = idx / 25600, rem = idx - kb * 25600;
        int n = rem >> 5, q8 = rem & 31;
        int k = kb * 32 + q8;
        WxP[idx] = (k < IN_ && kb < 25) ? (__bf16)Wx[(size_t)k * G4H_ + n] : (__bf16)0.0f;
    }
    if (idx < W2P_N) {
        int kb = idx >> 15;              // / (1024*32)
        int rem = idx & 32767;
        int n = rem >> 5, q8 = rem & 31;
        int kl = (kb < 12 ? kb : (kb < 24 ? kb - 12 : kb - 24)) * 32 + q8;
        __bf16 o = (__bf16)0.0f;
        float v = 0.f; bool has = false;
        if (n < G4H_) {
            if (kl < OUTF_) {
                v = (kl < H_) ? Wh[(size_t)kl * G4H_ + n]
                              : Wx[(size_t)(789 + kl - H_) * G4H_ + n];
                has = true;
            }
        } else if (n < G4H_ + PDIM_) {
            if (kl < H_) { v = Wp[(size_t)kl * PDIM_ + (n - G4H_)]; has = true; }
        }
        if (has) {
            __bf16 hi = (__bf16)v;
            o = (kb < 24) ? hi : (__bf16)(v - (float)hi);
        }
        W2P[idx] = o;
    }
}

// ---------------------------------------------------------------------------
// init state: memory, c, usage/read weights, Apack (h=0, r=1e-6), loss accum
// ---------------------------------------------------------------------------
__global__ void init_kernel(float* Cst, float* Mg, float* wug, float* wrg,
                            __bf16* Apack, float* scal)
{
    size_t i = (size_t)blockIdx.x * blockDim.x + threadIdx.x;
    size_t stride = (size_t)gridDim.x * blockDim.x;
    for (size_t j = i; j < (size_t)B_ * MSZ_; j += stride) Mg[j] = 1e-6f;
    for (size_t j = i; j < (size_t)B_ * H_; j += stride) Cst[j] = 0.f;
    for (size_t j = i; j < (size_t)B_ * N_; j += stride) wug[j] = ((j & (N_ - 1)) == 0) ? 1.f : 0.f;
    for (size_t j = i; j < (size_t)B_ * R_ * N_; j += stride) wrg[j] = ((j & (N_ - 1)) == 0) ? 1.f : 0.f;
    for (size_t j = i; j < (size_t)APK_N; j += stride) {
        int kb = (int)(j >> 15);
        int q8 = (int)(j & 31);
        int kl = (kb % 12) * 32 + q8;
        float v = (kl >= H_ && kl < OUTF_) ? 1e-6f : 0.f;
        __bf16 hi = (__bf16)v;
        Apack[j] = (kb < 12) ? hi : (__bf16)(v - (float)hi);
    }
    if (i < 2) scal[i] = 0.f;
}

// ---------------------------------------------------------------------------
// Convert ALL images to bf16 — unchanged (verified).
// ---------------------------------------------------------------------------
__global__ __launch_bounds__(256) void img_convert(
    const float* __restrict__ images, __bf16* __restrict__ img)
{
    long long gi = (long long)blockIdx.x * 256 + threadIdx.x;
    if (gi * 4 >= (long long)T_ * B_ * KP_) return;
    long long m = (gi * 4) / KP_;
    int k = (int)((gi * 4) - m * KP_);
    int t = (int)(m >> 10), b = (int)(m & (B_ - 1));
    bf16x4 o;
    if (k < IN_) {
        const float4 v = *(const float4*)&images[((size_t)b * T_ + t) * IN_ + k];
        o[0] = (__bf16)v.x; o[1] = (__bf16)v.y; o[2] = (__bf16)v.z; o[3] = (__bf16)v.w;
    } else {
        o[0] = o[1] = o[2] = o[3] = (__bf16)0.0f;
    }
    *(bf16x4*)&img[(size_t)m * KP_ + k] = o;
}

// ---------------------------------------------------------------------------
// Gx precompute — unchanged (verified, round 1).
// ---------------------------------------------------------------------------
__global__ __launch_bounds__(256) void gx_mfma(
    const __bf16* __restrict__ img, const __bf16* __restrict__ WxP,
    const int* __restrict__ labels, const float* __restrict__ Wx,
    const float* __restrict__ b_lstm, float* __restrict__ Gx)
{
    __shared__ __bf16 A_lds[4096];
    __shared__ __bf16 B_lds[5120];

    const int tid  = threadIdx.x;
    const int lane = tid & 63, w = tid >> 6;
    const int quad = lane >> 4, ln = lane & 15;
    const int swzl = (ln & 3) ^ ((ln >> 2) & 3);
    const int row0 = blockIdx.x * 128;
    const int n0   = blockIdx.y * 160;
    const int mw   = (w >> 1) * 64;
    const int nw   = (w & 1) * 80;

    fx4 acc[4][5];
    #pragma unroll
    for (int i = 0; i < 4; i++)
        #pragma unroll
        for (int j = 0; j < 5; j++) acc[i][j] = (fx4)0.0f;

    for (int kb = 0; kb < 25; kb++) {
        #pragma unroll
        for (int p = 0; p < 2; p++) {
            int cc = p * 256 + tid;
            int m = cc >> 2, c = cc & 3;
            int q = c ^ ((m & 3) ^ ((m >> 2) & 3));
            load_lds16(img + (size_t)(row0 + m) * KP_ + kb * 32 + q * 8,
                       &A_lds[(size_t)(p * 256 + w * 64) * 8]);
        }
        #pragma unroll
        for (int p = 0; p < 3; p++) {
            if (p * 4 + w < 10) {
                int cc = p * 256 + tid;
                int n = cc >> 2, c = cc & 3;
                int q = c ^ ((n & 3) ^ ((n >> 2) & 3));
                load_lds16(WxP + ((size_t)kb * G4H_ + n0 + n) * 32 + q * 8,
                           &B_lds[(size_t)(p * 256 + w * 64) * 8]);
            }
        }
        __syncthreads();

        bf16x8 a[4], bb[5];
        #pragma unroll
        for (int mi = 0; mi < 4; mi++)
            a[mi] = *(const bf16x8*)&A_lds[((mw + mi * 16 + ln) * 4 + (quad ^ swzl)) * 8];
        #pragma unroll
        for (int ni = 0; ni < 5; ni++)
            bb[ni] = *(const bf16x8*)&B_lds[((nw + ni * 16 + ln) * 4 + (quad ^ swzl)) * 8];
        #pragma unroll
        for (int mi = 0; mi < 4; mi++)
            #pragma unroll
            for (int ni = 0; ni < 5; ni++)
                acc[mi][ni] = __builtin_amdgcn_mfma_f32_16x16x32_bf16(a[mi], bb[ni], acc[mi][ni], 0, 0, 0);
        __syncthreads();
    }

    #pragma unroll
    for (int mi = 0; mi < 4; mi++) {
        #pragma unroll
        for (int rr = 0; rr < 4; rr++) {
            int row = row0 + mw + mi * 16 + quad * 4 + rr;
            int t = row >> 10, b = row & (B_ - 1);
            int lbl = (t > 0) ? labels[b * T_ + t - 1] : -1;
            #pragma unroll
            for (int ni = 0; ni < 5; ni++) {
                int col = n0 + nw + ni * 16 + ln;
                float add = b_lstm[col];
                if (lbl >= 0) add += Wx[(size_t)(IN_ + lbl) * G4H_ + col];
                Gx[(size_t)row * G4H_ + col] = acc[mi][ni][rr] + add;
            }
        }
    }
}

// ---------------------------------------------------------------------------
// rec_mfma v2: gates[b][0..799] = S@W2 + Gx_t; gates[b][800..963] = h@Wp + bp.
// 32x32 tiles, grid (32,32) = 1024 blocks = 4/CU (vs 1.56/CU before) so the
// 9 load->drain->MFMA rounds overlap across blocks. 4 waves, 1 frag/wave.
// K chain (kbg 0..35 ascending) identical to the verified round-1 kernel ->
// bit-identical gate values for cols < 800.
// ---------------------------------------------------------------------------
__global__ __launch_bounds__(256) void rec_mfma(
    const __bf16* __restrict__ Apack, const __bf16* __restrict__ W2P,
    const float* __restrict__ Gxt, const float* __restrict__ bp,
    float* __restrict__ gates)
{
    __shared__ __bf16 A_lds[4096];   // [kbl(4)][row(32)][chunk(4)] x8 : 8 KB
    __shared__ __bf16 B_lds[4096];   // [kbl(4)][n(32)][chunk(4)]   x8 : 8 KB

    const int tid  = threadIdx.x;
    const int lane = tid & 63, w = tid >> 6;
    const int quad = lane >> 4, ln = lane & 15;
    const int swzl = (ln & 3) ^ ((ln >> 2) & 3);
    const int row0 = blockIdx.x * 32;
    const int col0 = blockIdx.y * 32;
    const int mw   = (w >> 1) * 16;
    const int nw   = (w & 1) * 16;

    fx4 acc = (fx4)0.0f;

    for (int it = 0; it < 9; it++) {
        // stage A: 512 chunks (kbl 0..3, row 0..31, c 0..3), 2 passes
        #pragma unroll
        for (int p = 0; p < 2; p++) {
            int cc = p * 256 + tid;
            int kbl = cc >> 7, row = (cc >> 2) & 31, c = cc & 3;
            int q = c ^ ((row & 3) ^ ((row >> 2) & 3));
            int kbg = it * 4 + kbl;
            int kba = (kbg < AKB_) ? kbg : kbg - AKB_;
            load_lds16(Apack + ((size_t)kba * B_ + row0 + row) * 32 + q * 8,
                       &A_lds[(size_t)(p * 256 + w * 64) * 8]);
        }
        // stage B: 512 chunks
        #pragma unroll
        for (int p = 0; p < 2; p++) {
            int cc = p * 256 + tid;
            int kbl = cc >> 7, n = (cc >> 2) & 31, c = cc & 3;
            int q = c ^ ((n & 3) ^ ((n >> 2) & 3));
            int kbg = it * 4 + kbl;
            load_lds16(W2P + ((size_t)kbg * GSTR_ + col0 + n) * 32 + q * 8,
                       &B_lds[(size_t)(p * 256 + w * 64) * 8]);
        }
        __syncthreads();

        #pragma unroll
        for (int s = 0; s < 4; s++) {
            bf16x8 a0 = *(const bf16x8*)&A_lds[((s * 32 + mw + ln) * 4 + (quad ^ swzl)) * 8];
            bf16x8 b0 = *(const bf16x8*)&B_lds[((s * 32 + nw + ln) * 4 + (quad ^ swzl)) * 8];
            acc = __builtin_amdgcn_mfma_f32_16x16x32_bf16(a0, b0, acc, 0, 0, 0);
        }
        __syncthreads();
    }

    #pragma unroll
    for (int rr = 0; rr < 4; rr++) {
        int row = row0 + mw + quad * 4 + rr;
        int col = col0 + nw + ln;
        float add;
        if (col < G4H_)              add = Gxt[(size_t)row * G4H_ + col];
        else if (col < G4H_ + PDIM_) add = bp[col - G4H_];
        else                         add = 0.f;
        gates[(size_t)row * GSTR_ + col] = acc[rr] + add;
    }
}

// ---------------------------------------------------------------------------
// step_kernel v2: identical to the verified round-1 kernel except
//  (a) gates row stride 1024, (b) P2's Wp dot product replaced by a single
//  read of the MFMA-computed p pre-activation (gates cols 800..963).
// ---------------------------------------------------------------------------
__global__ __launch_bounds__(256) void step_kernel(
    const float* __restrict__ gates, __bf16* __restrict__ Apack, float* __restrict__ Cst,
    float* __restrict__ Mg, float* __restrict__ wug, float* __restrict__ wrg,
    const float* __restrict__ Wc, const float* __restrict__ bc,
    float* __restrict__ out, int t)
{
    const int b = blockIdx.x;
    const int tid = threadIdx.x;
    const int lane = tid & 63, w = tid >> 6;
    const int nn = tid >> 1, dh = tid & 1, d0 = dh * 20;

    __shared__ float M_s[N_ * MST_];
    __shared__ float h_s[H_];
    __shared__ float k_s[RD_];
    __shared__ float sig_s[R_];
    __shared__ float wu_s[N_];
    __shared__ int   lu_s[R_];
    __shared__ float wrn_s[R_ * N_];
    __shared__ float ww_s[R_ * N_];
    __shared__ float rn_s[RD_];
    __shared__ float red[160];

    float m[20];

    // P1: LSTM + state loads; M -> registers
    if (tid < H_) {
        const float gi = gates[(size_t)b * GSTR_ + tid];
        const float gf = gates[(size_t)b * GSTR_ + H_ + tid];
        const float gg = gates[(size_t)b * GSTR_ + 2 * H_ + tid];
        const float go = gates[(size_t)b * GSTR_ + 3 * H_ + tid];
        const float c_old = Cst[b * H_ + tid];
        const float cn = sigmoidf_(gf) * c_old + sigmoidf_(gi) * tanhf(gg);
        const float hn = sigmoidf_(go) * tanhf(cn);
        Cst[b * H_ + tid] = cn;
        h_s[tid] = hn;
        __bf16 hi = (__bf16)hn;
        __bf16 lo = (__bf16)(hn - (float)hi);
        const int kb = tid >> 5, q8 = tid & 31;
        Apack[((size_t)kb * B_ + b) * 32 + q8] = hi;
        Apack[((size_t)(kb + 12) * B_ + b) * 32 + q8] = lo;
    }
    if (tid < N_) wu_s[tid] = wug[b * N_ + tid];
    {
        const float* src = Mg + (size_t)b * MSZ_ + nn * D_ + d0;
        #pragma unroll
        for (int j = 0; j < 20; j += 4) {
            float4 v = *(const float4*)&src[j];
            m[j] = v.x; m[j + 1] = v.y; m[j + 2] = v.z; m[j + 3] = v.w;
        }
    }
    __syncthreads();

    // P2: read precomputed p (gates cols 800..963) || top-4 least-used (wave 3)
    if (tid < PDIM_) {
        float acc = gates[(size_t)b * GSTR_ + G4H_ + tid];
        int r = tid / (D_ + 1), d = tid - r * (D_ + 1);
        if (d < D_) k_s[r * D_ + d] = tanhf(acc);
        else        sig_s[r] = sigmoidf_(acc);
    }
    if (w == 3) {
        float v0 = wu_s[lane], v1 = wu_s[lane + 64];
        #pragma unroll
        for (int r4 = 0; r4 < R_; r4++) {
            float v; int idx;
            if (v1 < v0) { v = v1; idx = lane + 64; } else { v = v0; idx = lane; }
            #pragma unroll
            for (int off = 32; off > 0; off >>= 1) {
                float ov = __shfl_down(v, off);
                int   oi = __shfl_down(idx, off);
                if (ov < v || (ov == v && oi < idx)) { v = ov; idx = oi; }
            }
            int bi = __shfl(idx, 0);
            if (lane == 0) lu_s[r4] = bi;
            if (lane == bi) v0 = 3.0e38f;
            if (lane + 64 == bi) v1 = 3.0e38f;
        }
    }
    __syncthreads();

    // P3: cosine scores from register M
    {
        float nr = 0.f;
        #pragma unroll
        for (int j = 0; j < 20; j++) nr += m[j] * m[j];
        float dt[4];
        #pragma unroll
        for (int r = 0; r < 4; r++) {
            float s = 0.f;
            const float* kr = &k_s[r * D_ + d0];
            #pragma unroll
            for (int j = 0; j < 20; j += 4) {
                float4 kv = *(const float4*)&kr[j];
                s += m[j] * kv.x + m[j + 1] * kv.y + m[j + 2] * kv.z + m[j + 3] * kv.w;
            }
            dt[r] = s;
        }
        nr += __shfl_xor(nr, 1);
        #pragma unroll
        for (int r = 0; r < 4; r++) dt[r] += __shfl_xor(dt[r], 1);
        const float den = sqrtf(nr) + 1e-8f;
        if (dh == 0) { wrn_s[nn] = dt[0] / den;          wrn_s[N_ + nn] = dt[1] / den; }
        else         { wrn_s[2 * N_ + nn] = dt[2] / den; wrn_s[3 * N_ + nn] = dt[3] / den; }
    }
    __syncthreads();

    // P4: per-head softmax + write weights
    {
        const int r = w;
        float kv = (lane < D_) ? k_s[r * D_ + lane] * k_s[r * D_ + lane] : 0.f;
        #pragma unroll
        for (int off = 32; off > 0; off >>= 1) kv += __shfl_xor(kv, off);
        const float kinv = 1.f / (sqrtf(kv) + 1e-8f);

        const int n0i = lane, n1i = lane + 64;
        float s0 = wrn_s[r * N_ + n0i] * kinv;
        float s1 = wrn_s[r * N_ + n1i] * kinv;
        const float sg = sig_s[r];
        float wlu0 = (n0i == lu_s[0] || n0i == lu_s[1] || n0i == lu_s[2] || n0i == lu_s[3]) ? 1.f : 0.f;
        float wlu1 = (n1i == lu_s[0] || n1i == lu_s[1] || n1i == lu_s[2] || n1i == lu_s[3]) ? 1.f : 0.f;
        ww_s[r * N_ + n0i] = sg * wrg[(size_t)b * (R_ * N_) + r * N_ + n0i] + (1.f - sg) * wlu0;
        ww_s[r * N_ + n1i] = sg * wrg[(size_t)b * (R_ * N_) + r * N_ + n1i] + (1.f - sg) * wlu1;
        float mx = fmaxf(s0, s1);
        #pragma unroll
        for (int off = 32; off > 0; off >>= 1) mx = fmaxf(mx, __shfl_xor(mx, off));
        float e0 = expf(s0 - mx), e1 = expf(s1 - mx);
        float sm = e0 + e1;
        #pragma unroll
        for (int off = 32; off > 0; off >>= 1) sm += __shfl_xor(sm, off);
        const float inv = 1.f / sm;
        e0 *= inv; e1 *= inv;
        wrn_s[r * N_ + n0i] = e0;
        wrn_s[r * N_ + n1i] = e1;
        wrg[(size_t)b * (R_ * N_) + r * N_ + n0i] = e0;
        wrg[(size_t)b * (R_ * N_) + r * N_ + n1i] = e1;
    }
    __syncthreads();

    // P5: usage update + memory erase/write (register M)
    if (tid < N_) {
        float acc = GAMMA_ * wu_s[tid];
        #pragma unroll
        for (int r = 0; r < R_; r++) acc += wrn_s[r * N_ + tid] + ww_s[r * N_ + tid];
        wug[b * N_ + tid] = acc;
    }
    {
        const int lu4 = lu_s[3];
        if (nn == lu4) {
            #pragma unroll
            for (int j = 0; j < 20; j++) m[j] = 0.f;
        }
        float wgt[4];
        #pragma unroll
        for (int r = 0; r < 4; r++) wgt[r] = ww_s[r * N_ + nn];
        #pragma unroll
        for (int r = 0; r < 4; r++) {
            const float* kr = &k_s[r * D_ + d0];
            const float g = wgt[r];
            #pragma unroll
            for (int j = 0; j < 20; j += 4) {
                float4 kv = *(const float4*)&kr[j];
                m[j]     += g * kv.x;
                m[j + 1] += g * kv.y;
                m[j + 2] += g * kv.z;
                m[j + 3] += g * kv.w;
            }
        }
        float* mrow = &M_s[nn * MST_ + d0];
        float* gdst = Mg + (size_t)b * MSZ_ + nn * D_ + d0;
        #pragma unroll
        for (int j = 0; j < 20; j += 4) {
            *(float2*)&mrow[j]     = make_float2(m[j], m[j + 1]);
            *(float2*)&mrow[j + 2] = make_float2(m[j + 2], m[j + 3]);
            *(float4*)&gdst[j]     = make_float4(m[j], m[j + 1], m[j + 2], m[j + 3]);
        }
    }
    __syncthreads();

    // P6: read vectors; write r to Apack (hi/lo)
    if (tid < RD_) {
        const int r = tid / D_, d = tid - r * D_;
        const float* wrow = &wrn_s[r * N_];
        float a0 = 0.f, a1 = 0.f, a2 = 0.f, a3 = 0.f;
        #pragma unroll 8
        for (int n2 = 0; n2 < N_; n2 += 4) {
            float4 wv = *(const float4*)&wrow[n2];
            a0 += wv.x * M_s[(n2 + 0) * MST_ + d];
            a1 += wv.y * M_s[(n2 + 1) * MST_ + d];
            a2 += wv.z * M_s[(n2 + 2) * MST_ + d];
            a3 += wv.w * M_s[(n2 + 3) * MST_ + d];
        }
        const float acc = (a0 + a1) + (a2 + a3);
        rn_s[tid] = acc;
        __bf16 hi = (__bf16)acc;
        __bf16 lo = (__bf16)(acc - (float)hi);
        const int kp = H_ + tid;
        const int kb = kp >> 5, q8 = kp & 31;
        Apack[((size_t)kb * B_ + b) * 32 + q8] = hi;
        Apack[((size_t)(kb + 12) * B_ + b) * 32 + q8] = lo;
    }
    __syncthreads();

    // P7: logits partials
    if (tid < 160) {
        int c = tid >> 5, seg = tid & 31;
        float acc = 0.f;
        for (int j = seg; j < OUTF_; j += 32) {
            float v = (j < H_) ? h_s[j] : rn_s[j - H_];
            acc += v * Wc[j * C_ + c];
        }
        red[tid] = acc;
    }
    __syncthreads();

    // P8: finish logits, softmax, write probs
    if (w == 0) {
        float lg = 0.f;
        if (lane < C_) {
            lg = bc[lane];
            #pragma unroll
            for (int s = 0; s < 32; s++) lg += red[lane * 32 + s];
        }
        float l0 = __shfl(lg, 0), l1 = __shfl(lg, 1), l2 = __shfl(lg, 2);
        float l3 = __shfl(lg, 3), l4 = __shfl(lg, 4);
        if (lane == 0) {
            float mx = fmaxf(fmaxf(fmaxf(l0, l1), fmaxf(l2, l3)), l4);
            float e0 = expf(l0 - mx), e1 = expf(l1 - mx), e2 = expf(l2 - mx);
            float e3 = expf(l3 - mx), e4 = expf(l4 - mx);
            float inv = 1.f / (e0 + e1 + e2 + e3 + e4);
            float* o = out + ((size_t)b * T_ + t) * C_;
            o[0] = e0 * inv; o[1] = e1 * inv; o[2] = e2 * inv; o[3] = e3 * inv; o[4] = e4 * inv;
        }
    }
}

// ---------------------------------------------------------------------------
// loss — unchanged (verified).
// ---------------------------------------------------------------------------
__global__ __launch_bounds__(256) void loss_kernel(
    const float* __restrict__ out, const int* __restrict__ labels, float* __restrict__ la)
{
    int row = blockIdx.x * 256 + threadIdx.x;
    float li = 0.f, ai = 0.f;
    if (row < B_ * T_) {
        float p[C_];
        #pragma unroll
        for (int c = 0; c < C_; c++) p[c] = out[(size_t)row * C_ + c];
        int tgt = labels[row];
        float mx = p[0];
        #pragma unroll
        for (int c = 1; c < C_; c++) mx = fmaxf(mx, p[c]);
        float sm = 0.f;
        #pragma unroll
        for (int c = 0; c < C_; c++) sm += expf(p[c] - mx);
        li = (mx + logf(sm) - p[tgt]) * (1.f / (B_ * T_));
        int pred = 0; float bv = p[0];
        #pragma unroll
        for (int c = 1; c < C_; c++) if (p[c] > bv) { bv = p[c]; pred = c; }
        ai = (pred == tgt) ? (1.f / (B_ * T_)) : 0.f;
    }
    for (int off = 32; off > 0; off >>= 1) {
        li += __shfl_down(li, off);
        ai += __shfl_down(ai, off);
    }
    if ((threadIdx.x & 63) == 0) {
        atomicAdd(&la[0], li);
        atomicAdd(&la[1], ai);
    }
}

extern "C" void kernel_launch(void* const* d_in, const int* in_sizes, int n_in,
                              void* d_out, int out_size, void* d_ws, size_t ws_size,
                              hipStream_t stream)
{
    const float* images = (const float*)d_in[0];
    const int*   labels = (const int*)d_in[1];
    const float* Wx     = (const float*)d_in[2];
    const float* Wh     = (const float*)d_in[3];
    const float* b_lstm = (const float*)d_in[4];
    const float* Wp     = (const float*)d_in[5];
    const float* bp     = (const float*)d_in[6];
    const float* Wc     = (const float*)d_in[7];
    const float* bc     = (const float*)d_in[8];
    float* out = (float*)d_out;

    float* ws = (float*)d_ws;
    float* gates = ws;                             // 1024*1024 f32 (4 MB)
    float* Cst   = gates + (size_t)B_ * GSTR_;     // 1024*200
    float* Mg    = Cst   + (size_t)B_ * H_;        // 1024*5120
    float* wug   = Mg    + (size_t)B_ * MSZ_;      // 1024*128
    float* wrg   = wug   + (size_t)B_ * N_;        // 1024*512
    float* Gx    = wrg   + (size_t)B_ * R_ * N_;   // 50*1024*800 f32 (164 MB)
    __bf16* imgb = (__bf16*)(Gx + (size_t)T_ * B_ * G4H_);   // 50*1024*800 bf16 (82 MB)
    __bf16* WxP  = imgb + (size_t)T_ * B_ * KP_;             // 643072
    __bf16* W2P  = WxP  + (size_t)WXP_N;                     // 1179648
    __bf16* Apack = W2P + (size_t)W2P_N;                     // 786432
    // total ~280 MB

    pack_kernel<<<(W2P_N + 255) / 256, 256, 0, stream>>>(Wx, Wh, Wp, WxP, W2P);
    init_kernel<<<1024, 256, 0, stream>>>(Cst, Mg, wug, wrg, Apack, out + (size_t)B_ * T_ * C_);

    img_convert<<<(int)(((long long)T_ * B_ * KP_ / 4 + 255) / 256), 256, 0, stream>>>(images, imgb);
    gx_mfma<<<dim3(T_ * B_ / 128, 5), 256, 0, stream>>>(imgb, WxP, labels, Wx, b_lstm, Gx);

    for (int t = 0; t < T_; t++) {
        rec_mfma<<<dim3(B_ / 32, GSTR_ / 32), 256, 0, stream>>>(
            Apack, W2P, Gx + (size_t)t * B_ * G4H_, bp, gates);
        step_kernel<<<B_, 256, 0, stream>>>(
            gates, Apack, Cst, Mg, wug, wrg, Wc, bc, out, t);
    }

    loss_kernel<<<(B_ * T_) / 256, 256, 0, stream>>>(out, labels, out + (size_t)B_ * T_ * C_);
}